// Round 8
// baseline (581.911 us; speedup 1.0000x reference)
//
#include <hip/hip_runtime.h>
#include <hip/hip_bf16.h>
#include <cstdint>

typedef unsigned short u16;
typedef __bf16 bf16x8 __attribute__((ext_vector_type(8)));
typedef float floatx4 __attribute__((ext_vector_type(4)));

// round-to-nearest-even f32 -> bf16 bits
static __device__ __forceinline__ u16 f2bf(float f) {
    union { float f; unsigned int u; } v; v.f = f;
    unsigned int u = v.u;
    return (u16)((u + 0x7FFFu + ((u >> 16) & 1u)) >> 16);
}

// ---------------------------------------------------------------------------
// prep (unchanged from R11, passed): [0,1024) w1-T, [1024,2048) w2-T,
// [2048,10240) LayerNorm rows. 128x32 transpose tiles, 256B out segments.
// ---------------------------------------------------------------------------
__device__ __forceinline__ void transpose_body(
    const float* __restrict__ in, u16* __restrict__ out,
    int R, int Ccols, int bx, int by, int tid, float (*tile)[33])
{
    const int r0 = by * 128, c0 = bx * 32;
#pragma unroll
    for (int p = 0; p < 4; ++p) {
        const int f = p * 256 + tid;
        const int r = f >> 3, c4 = (f & 7) * 4;
        const float4 v = *(const float4*)&in[(size_t)(r0 + r) * Ccols + c0 + c4];
        tile[r][c4 + 0] = v.x; tile[r][c4 + 1] = v.y;
        tile[r][c4 + 2] = v.z; tile[r][c4 + 3] = v.w;
    }
    __syncthreads();
    const int wv = tid >> 6, ln = tid & 63;
#pragma unroll
    for (int i = 0; i < 8; ++i) {
        const int c = i * 4 + wv;
        ushort2 o = { f2bf(tile[ln * 2][c]), f2bf(tile[ln * 2 + 1][c]) };
        *(ushort2*)&out[(size_t)(c0 + c) * R + r0 + ln * 2] = o;
    }
}

__global__ __launch_bounds__(256)
void prep(const float* __restrict__ w1, const float* __restrict__ w2,
          const float* __restrict__ act, const float* __restrict__ ln_scale,
          const float* __restrict__ ln_bias,
          u16* __restrict__ W1t, u16* __restrict__ W2t, u16* __restrict__ X)
{
    __shared__ float tile[128][33];
    const int id  = blockIdx.x;
    const int tid = threadIdx.x;

    if (id < 1024) {
        transpose_body(w1, W1t, 1024, 4096, id & 127, id >> 7, tid, tile);
        return;
    }
    if (id < 2048) {
        const int t = id - 1024;
        transpose_body(w2, W2t, 4096, 1024, t & 31, t >> 5, tid, tile);
        return;
    }
    const int row = id - 2048;
    const float4 v = ((const float4*)(act + (size_t)row * 1024))[tid];
    float s  = v.x + v.y + v.z + v.w;
    float ss = v.x * v.x + v.y * v.y + v.z * v.z + v.w * v.w;
#pragma unroll
    for (int off = 32; off > 0; off >>= 1) {
        s  += __shfl_xor(s, off, 64);
        ss += __shfl_xor(ss, off, 64);
    }
    float* red = &tile[0][0];
    const int wave = tid >> 6, lane = tid & 63;
    if (lane == 0) { red[wave] = s; red[4 + wave] = ss; }
    __syncthreads();
    s  = red[0] + red[1] + red[2] + red[3];
    ss = red[4] + red[5] + red[6] + red[7];
    const float mu  = s * (1.0f / 1024.0f);
    const float var = ss * (1.0f / 1024.0f) - mu * mu;
    const float rs  = rsqrtf(var + 1e-5f);
    const float4 sc = ((const float4*)ln_scale)[tid];
    const float4 bi = ((const float4*)ln_bias)[tid];
    ushort4 o;
    o.x = f2bf((v.x - mu) * rs * sc.x + bi.x);
    o.y = f2bf((v.y - mu) * rs * sc.y + bi.y);
    o.z = f2bf((v.z - mu) * rs * sc.z + bi.z);
    o.w = f2bf((v.w - mu) * rs * sc.w + bi.w);
    ((ushort4*)(X + (size_t)row * 1024))[tid] = o;
}

// ---------------------------------------------------------------------------
// R14 GEMM: all-register streaming, NO LDS / NO barriers / NO manual waitcnt.
//
//   C[M][N] = A[M][K] * Bt[N][K]^T + bias (+ReLU)
//
// Rationale (R11 counters + R12/R13 NaN post-mortem): both GEMMs were
// LDS-port-bound (192KB frag reads/tile ~ MFMA cycles), and the mixed
// vmcnt queue (plain loads + LDS-DMA) in R12/R13 is the suspected NaN
// mechanism -- no reference kernel mixes the two under counted waits.
// Both operands are K-major, so MFMA fragments ARE contiguous 16B global
// loads per lane: LDS was only a bandwidth cache for x2/x4 intra-CU
// duplication, which L1 (32KB, ~24KB working set/kh) catches instead.
// Beyond-L1 traffic per CU-tile equals what staging fetched -> L2/L3
// demand unchanged vs R11. Everything is compiler-visible; the backend's
// own counted vmcnt does all ordering. Zero race surface.
//
// Geometry: 512 thr = 8 waves (4M x 2N), wave tile 64x64, block 256x128.
// K-step 32 (one MFMA K), 4 fragment generations (named arrays, static
// indices only -- rule #20), depth-2 prefetch: load kt+2 while MFMA kt
// (~620cy/wave of MFMA between issue and use, 2 waves/SIMD double that).
// grid: gemm1 (M/256)*(N/128) = 32*32 = 1024; gemm2 32*8 = 256.
// ---------------------------------------------------------------------------
#define LOADG(g, ks)                                                          \
    do {                                                                      \
        _Pragma("unroll")                                                     \
        for (int mi = 0; mi < 4; ++mi)                                        \
            fa##g[mi] = *(const bf16x8*)(Ap + (size_t)mi * 16 * K +           \
                                         (size_t)(ks) * 32);                  \
        _Pragma("unroll")                                                     \
        for (int ni = 0; ni < 4; ++ni)                                        \
            fb##g[ni] = *(const bf16x8*)(Bp + (size_t)ni * 16 * K +           \
                                         (size_t)(ks) * 32);                  \
    } while (0)

#define MMAG(g)                                                               \
    do {                                                                      \
        _Pragma("unroll")                                                     \
        for (int mi = 0; mi < 4; ++mi)                                        \
            _Pragma("unroll")                                                 \
            for (int ni = 0; ni < 4; ++ni)                                    \
                acc[mi][ni] = __builtin_amdgcn_mfma_f32_16x16x32_bf16(        \
                    fb##g[ni], fa##g[mi], acc[mi][ni], 0, 0, 0);              \
    } while (0)

template <int K, bool BF16_OUT, bool RELU>
__global__ __launch_bounds__(512, 2)
void gemm_reg(const u16* __restrict__ A, const u16* __restrict__ Bt,
              const float* __restrict__ bias, void* __restrict__ Cout,
              int M, int N)
{
    const int tid  = threadIdx.x;
    const int wave = tid >> 6;
    const int lane = tid & 63;
    const int quad = lane >> 4;
    const int l16  = lane & 15;
    const int wm   = wave >> 1;            // 0..3 -> 64-row stripe
    const int wn   = wave & 1;             // 0..1 -> 64-col stripe

    const int nbm = M >> 8;
    const int id  = blockIdx.x;
    const int bm  = id % nbm;              // bm-fastest (R5: swizzles hurt)
    const int bn  = id / nbm;

    // per-lane fragment base pointers (16B contiguous per load)
    const u16* Ap = A  + (size_t)(bm * 256 + wm * 64 + l16) * K + quad * 8;
    const u16* Bp = Bt + (size_t)(bn * 128 + wn * 64 + l16) * K + quad * 8;

    bf16x8 fa0[4], fb0[4], fa1[4], fb1[4];
    bf16x8 fa2[4], fb2[4], fa3[4], fb3[4];

    floatx4 acc[4][4];
#pragma unroll
    for (int i = 0; i < 4; ++i)
#pragma unroll
        for (int j = 0; j < 4; ++j)
            acc[i][j] = (floatx4){0.f, 0.f, 0.f, 0.f};

    constexpr int NT = K / 32;             // 32 (gemm1) / 128 (gemm2)
    constexpr int NI = NT / 4;

    // prologue: generations 0,1 <- k-steps 0,1
    LOADG(0, 0);
    LOADG(1, 1);

    for (int i = 0; i < NI - 1; ++i) {
        const int b = 4 * i;
        LOADG(2, b + 2); MMAG(0);          // MFMA kt=b   ; load kt=b+2
        LOADG(3, b + 3); MMAG(1);          // MFMA kt=b+1 ; load kt=b+3
        LOADG(0, b + 4); MMAG(2);          // MFMA kt=b+2 ; load kt=b+4
        LOADG(1, b + 5); MMAG(3);          // MFMA kt=b+3 ; load kt=b+5
    }
    // epilogue: base = NT-4 (gen0 <- NT-4, gen1 <- NT-3 already loaded)
    LOADG(2, NT - 2); MMAG(0);
    LOADG(3, NT - 1); MMAG(1);
    MMAG(2);
    MMAG(3);

    // epilogue: lane (l16, quad) of acc[mi][ni] holds
    //   C[m = mbase+mi*16+l16][n = nbase+ni*16+quad*4 + r], r=0..3 contiguous
    const int mbase = bm * 256 + wm * 64;
    const int nbase = bn * 128 + wn * 64;
#pragma unroll
    for (int mi = 0; mi < 4; ++mi) {
        const int m = mbase + mi * 16 + l16;
#pragma unroll
        for (int ni = 0; ni < 4; ++ni) {
            const int n0 = nbase + ni * 16 + quad * 4;
            const float4 bv = *(const float4*)&bias[n0];
            float v0 = acc[mi][ni][0] + bv.x;
            float v1 = acc[mi][ni][1] + bv.y;
            float v2 = acc[mi][ni][2] + bv.z;
            float v3 = acc[mi][ni][3] + bv.w;
            if (RELU) {
                v0 = fmaxf(v0, 0.f); v1 = fmaxf(v1, 0.f);
                v2 = fmaxf(v2, 0.f); v3 = fmaxf(v3, 0.f);
            }
            if (BF16_OUT) {
                ushort4 o = { f2bf(v0), f2bf(v1), f2bf(v2), f2bf(v3) };
                *(ushort4*)&((u16*)Cout)[(size_t)m * N + n0] = o;
            } else {
                float4 o = { v0, v1, v2, v3 };
                *(float4*)&((float*)Cout)[(size_t)m * N + n0] = o;
            }
        }
    }
}

// ---------------------------------------------------------------------------
// inputs: 0 act(4,2048,1024) f32, 1 mask(unused), 2 ln_scale(1024),
//         3 ln_bias(1024), 4 w1(1024,4096), 5 b1(4096), 6 w2(4096,1024),
//         7 b2(1024). out: (4,2048,1024) f32.
// ws (bf16 bits): X[8192*1024] | W1t[4096*1024] | W2t[1024*4096] | H[8192*4096]
// ---------------------------------------------------------------------------
extern "C" void kernel_launch(void* const* d_in, const int* in_sizes, int n_in,
                              void* d_out, int out_size, void* d_ws, size_t ws_size,
                              hipStream_t stream)
{
    const float* act      = (const float*)d_in[0];
    const float* ln_scale = (const float*)d_in[2];
    const float* ln_bias  = (const float*)d_in[3];
    const float* w1       = (const float*)d_in[4];
    const float* b1       = (const float*)d_in[5];
    const float* w2       = (const float*)d_in[6];
    const float* b2       = (const float*)d_in[7];
    float* out = (float*)d_out;

    const int M = 8192, C = 1024, CI = 4096;

    u16* X   = (u16*)d_ws;                 // [M][C]
    u16* W1t = X   + (size_t)M * C;        // [CI][C]
    u16* W2t = W1t + (size_t)CI * C;       // [C][CI]
    u16* H   = W2t + (size_t)C * CI;       // [M][CI]

    prep<<<10240, 256, 0, stream>>>(w1, w2, act, ln_scale, ln_bias, W1t, W2t, X);
    // H = relu(X @ W1 + b1): 1024 blocks, all-register streaming GEMM
    gemm_reg<1024, true, true><<<(M / 256) * (CI / 128), 512, 0, stream>>>(
        X, W1t, b1, (void*)H, M, CI);
    // out = H @ W2 + b2: 256 blocks = 1/CU
    gemm_reg<4096, false, false><<<(M / 256) * (C / 128), 512, 0, stream>>>(
        H, W2t, b2, (void*)out, M, C);
}

// Round 9
// 248.845 us; speedup vs baseline: 2.3385x; 2.3385x over previous
//
#include <hip/hip_runtime.h>
#include <hip/hip_bf16.h>
#include <cstdint>

typedef unsigned short u16;
typedef __bf16 bf16x8 __attribute__((ext_vector_type(8)));
typedef float floatx4 __attribute__((ext_vector_type(4)));

#define AS1 __attribute__((address_space(1)))
#define AS3 __attribute__((address_space(3)))

#define SCHED0  __builtin_amdgcn_sched_barrier(0)
#define BARRIER __builtin_amdgcn_s_barrier()

// round-to-nearest-even f32 -> bf16 bits
static __device__ __forceinline__ u16 f2bf(float f) {
    union { float f; unsigned int u; } v; v.f = f;
    unsigned int u = v.u;
    return (u16)((u + 0x7FFFu + ((u >> 16) & 1u)) >> 16);
}

// LDS byte offset of a __shared__ address (AS3 pointers are 32-bit)
static __device__ __forceinline__ unsigned lds_off(const u16* p) {
    return (unsigned)(unsigned long long)(const AS3 u16*)p;
}
// inline-asm ds_read_b128; "=&v" early-clobber; manual counted lgkmcnt +
// SCHED0 order the consumers (rule #18).
static __device__ __forceinline__ bf16x8 ds_read8(unsigned off) {
    bf16x8 r;
    asm volatile("ds_read_b128 %0, %1" : "=&v"(r) : "v"(off));
    return r;
}

template <int N> __device__ __forceinline__ void wvm() {
    if constexpr (N == 0) asm volatile("s_waitcnt vmcnt(0)" ::: "memory");
    else if constexpr (N == 3) asm volatile("s_waitcnt vmcnt(3)" ::: "memory");
    else if constexpr (N == 6) asm volatile("s_waitcnt vmcnt(6)" ::: "memory");
}
template <int N> __device__ __forceinline__ void wlg() {
    if constexpr (N == 0) asm volatile("s_waitcnt lgkmcnt(0)" ::: "memory");
    else if constexpr (N == 4) asm volatile("s_waitcnt lgkmcnt(4)" ::: "memory");
    else if constexpr (N == 8) asm volatile("s_waitcnt lgkmcnt(8)" ::: "memory");
}

// ---------------------------------------------------------------------------
// prep (verbatim R11, passed): [0,1024) w1-T, [1024,2048) w2-T,
// [2048,10240) LayerNorm rows. 128x32 transpose tiles, 256B out segments.
// ---------------------------------------------------------------------------
__device__ __forceinline__ void transpose_body(
    const float* __restrict__ in, u16* __restrict__ out,
    int R, int Ccols, int bx, int by, int tid, float (*tile)[33])
{
    const int r0 = by * 128, c0 = bx * 32;
#pragma unroll
    for (int p = 0; p < 4; ++p) {
        const int f = p * 256 + tid;
        const int r = f >> 3, c4 = (f & 7) * 4;
        const float4 v = *(const float4*)&in[(size_t)(r0 + r) * Ccols + c0 + c4];
        tile[r][c4 + 0] = v.x; tile[r][c4 + 1] = v.y;
        tile[r][c4 + 2] = v.z; tile[r][c4 + 3] = v.w;
    }
    __syncthreads();
    const int wv = tid >> 6, ln = tid & 63;
#pragma unroll
    for (int i = 0; i < 8; ++i) {
        const int c = i * 4 + wv;
        ushort2 o = { f2bf(tile[ln * 2][c]), f2bf(tile[ln * 2 + 1][c]) };
        *(ushort2*)&out[(size_t)(c0 + c) * R + r0 + ln * 2] = o;
    }
}

__global__ __launch_bounds__(256)
void prep(const float* __restrict__ w1, const float* __restrict__ w2,
          const float* __restrict__ act, const float* __restrict__ ln_scale,
          const float* __restrict__ ln_bias,
          u16* __restrict__ W1t, u16* __restrict__ W2t, u16* __restrict__ X)
{
    __shared__ float tile[128][33];
    const int id  = blockIdx.x;
    const int tid = threadIdx.x;

    if (id < 1024) {
        transpose_body(w1, W1t, 1024, 4096, id & 127, id >> 7, tid, tile);
        return;
    }
    if (id < 2048) {
        const int t = id - 1024;
        transpose_body(w2, W2t, 4096, 1024, t & 31, t >> 5, tid, tile);
        return;
    }
    const int row = id - 2048;
    const float4 v = ((const float4*)(act + (size_t)row * 1024))[tid];
    float s  = v.x + v.y + v.z + v.w;
    float ss = v.x * v.x + v.y * v.y + v.z * v.z + v.w * v.w;
#pragma unroll
    for (int off = 32; off > 0; off >>= 1) {
        s  += __shfl_xor(s, off, 64);
        ss += __shfl_xor(ss, off, 64);
    }
    float* red = &tile[0][0];
    const int wave = tid >> 6, lane = tid & 63;
    if (lane == 0) { red[wave] = s; red[4 + wave] = ss; }
    __syncthreads();
    s  = red[0] + red[1] + red[2] + red[3];
    ss = red[4] + red[5] + red[6] + red[7];
    const float mu  = s * (1.0f / 1024.0f);
    const float var = ss * (1.0f / 1024.0f) - mu * mu;
    const float rs  = rsqrtf(var + 1e-5f);
    const float4 sc = ((const float4*)ln_scale)[tid];
    const float4 bi = ((const float4*)ln_bias)[tid];
    ushort4 o;
    o.x = f2bf((v.x - mu) * rs * sc.x + bi.x);
    o.y = f2bf((v.y - mu) * rs * sc.y + bi.y);
    o.z = f2bf((v.z - mu) * rs * sc.z + bi.z);
    o.w = f2bf((v.w - mu) * rs * sc.w + bi.w);
    ((ushort4*)(X + (size_t)row * 1024))[tid] = o;
}

// ---------------------------------------------------------------------------
// R15 GEMM1: H = relu(X @ W1t^T + b1), bf16.  M=8192 N=4096 K=1024.
// BM=BN=256, BK=64, 8 waves (2M x 4N), wave tile 128x64, acc[8][4].
// KH-MAJOR 4-phase schedule (balanced reads 8/4/4/8, all one phase ahead):
//   p0: MFMA mi0-3 kh0 (afrX,bres0); read A47kh0->afrY + Bkh1->bres1
//   p1: MFMA mi4-7 kh0 (afrY,bres0); read A03kh1->afrX
//   p2: MFMA mi0-3 kh1 (afrX,bres1); read A47kh1->afrY;  vmcnt(0) post-MFMA
//   p3: MFMA mi4-7 kh1 (afrY,bres1); read A03kh0(t+1)->afrX + Bkh0(t+1)->bres0
// lgkm ledger (DS-only queue, oldest-first; traced):
//   enter p0: Q=[A03kh0,Bkh0]x4 (8). p0 +8 -> wlg<8> retires those 8.
//   p1 +4 (Q=[afrY4,bres1_4,afrX4]) -> wlg<8> retires afrY.
//   p2 +4 -> wlg<4> retires bres1+afrX, leaves afrY.
//   p3 +8 -> wlg<8> retires afrY, leaves 8 = steady. Tail: p3 wlg<0>.
// Staging (dbuf): p0: A0,A2,A1,A3(t+1); p1: B0..B3(t+1). Single vm wait:
// p2-end vmcnt(0), slack >=1.5 phases, panels L2-hot (16-32 blocks share).
// Race: buf(t-1)'s last reads (p2's afrY) retire at p3-start wlg<8>, one
// barrier before p0(t) staging -> safe. One barrier per phase.
// Swizzle: store slot s^(row&7), read slot (kh*4+quad)^(l16&7) (0-conflict).
// ---------------------------------------------------------------------------
__global__ __launch_bounds__(512, 2)
void gemm1(const u16* __restrict__ A, const u16* __restrict__ Bt,
           const float* __restrict__ bias, u16* __restrict__ H)
{
    constexpr int K = 1024, N = 4096;
    constexpr int ASZ = 256 * 64;        // u16 per buffer (32KB)
    __shared__ __align__(16) u16 Alds[2 * ASZ];
    __shared__ __align__(16) u16 Blds[2 * ASZ];

    const int tid  = threadIdx.x;
    const int wave = tid >> 6;
    const int lane = tid & 63;
    const int srow = lane >> 3;
    const int sst  = lane & 7;
    const int quad = lane >> 4;
    const int l16  = lane & 15;
    const int rkey = l16 & 7;
    const int wm   = wave >> 2;          // 0..1
    const int wn   = wave & 3;           // 0..3

    const int id = blockIdx.x;
    const int bm = id & 31;              // bm-fastest
    const int bn = id >> 5;              // 0..15

    const u16* Ag = A  + (size_t)bm * 256 * K;
    const u16* Bg = Bt + (size_t)bn * 256 * K;

    auto stA = [&](int buf, int c, int k0) {
        const int row = c * 64 + wave * 8 + srow;
        const int col = (sst ^ (row & 7)) * 8;
        __builtin_amdgcn_global_load_lds(
            (AS1 void*)(Ag + (size_t)row * K + k0 + col),
            (AS3 void*)(&Alds[buf * ASZ + c * 4096 + wave * 512]), 16, 0, 0);
    };
    auto stB = [&](int buf, int c, int k0) {
        const int row = c * 64 + wave * 8 + srow;
        const int col = (sst ^ (row & 7)) * 8;
        __builtin_amdgcn_global_load_lds(
            (AS1 void*)(Bg + (size_t)row * K + k0 + col),
            (AS3 void*)(&Blds[buf * ASZ + c * 4096 + wave * 512]), 16, 0, 0);
    };

    const unsigned Abase = lds_off(&Alds[0]);
    const unsigned Bbase = lds_off(&Blds[0]);
    unsigned aoff[8][2], boff[4][2];     // byte offsets within a buffer
#pragma unroll
    for (int mi = 0; mi < 8; ++mi)
#pragma unroll
        for (int kh = 0; kh < 2; ++kh)
            aoff[mi][kh] = ((wm * 128 + mi * 16 + l16) * 64 +
                            ((kh * 4 + quad) ^ rkey) * 8) * 2;
#pragma unroll
    for (int ni = 0; ni < 4; ++ni)
#pragma unroll
        for (int kh = 0; kh < 2; ++kh)
            boff[ni][kh] = ((wn * 64 + ni * 16 + l16) * 64 +
                            ((kh * 4 + quad) ^ rkey) * 8) * 2;

    floatx4 acc[8][4];
#pragma unroll
    for (int i = 0; i < 8; ++i)
#pragma unroll
        for (int j = 0; j < 4; ++j)
            acc[i][j] = (floatx4){0.f, 0.f, 0.f, 0.f};

    constexpr int NT = K / 64;           // 16

    // prologue: tile0 -> buf0; drain; pre-read p0's inputs (8 DS ops live)
    stA(0, 0, 0); stA(0, 2, 0); stA(0, 1, 0); stA(0, 3, 0);
    stB(0, 0, 0); stB(0, 1, 0); stB(0, 2, 0); stB(0, 3, 0);
    wvm<0>();
    SCHED0; BARRIER; SCHED0;

    bf16x8 afrX[4], afrY[4], bres0[4], bres1[4];
#pragma unroll
    for (int j = 0; j < 4; ++j) afrX[j] = ds_read8(Abase + aoff[j][0]);
#pragma unroll
    for (int ni = 0; ni < 4; ++ni) bres0[ni] = ds_read8(Bbase + boff[ni][0]);

    for (int t = 0; t < NT; ++t) {
        const int cur = t & 1, nb = cur ^ 1;
        const unsigned ab0 = Abase + (unsigned)(cur * ASZ * 2);
        const unsigned bb0 = Bbase + (unsigned)(cur * ASZ * 2);
        const unsigned abn = Abase + (unsigned)(nb * ASZ * 2);
        const unsigned bbn = Bbase + (unsigned)(nb * ASZ * 2);
        const int k1 = (t + 1) * 64;
        const bool st = (t + 1 < NT);

        // ---- p0: MFMA mi0-3 kh0; read afrY(A47kh0), bres1(Bkh1); stage A
#pragma unroll
        for (int j = 0; j < 4; ++j) afrY[j] = ds_read8(ab0 + aoff[4 + j][0]);
#pragma unroll
        for (int ni = 0; ni < 4; ++ni) bres1[ni] = ds_read8(bb0 + boff[ni][1]);
        if (st) { stA(nb, 0, k1); stA(nb, 2, k1); stA(nb, 1, k1); stA(nb, 3, k1); }
        wlg<8>();
        SCHED0;
        __builtin_amdgcn_s_setprio(1);
#pragma unroll
        for (int j = 0; j < 4; ++j)
#pragma unroll
            for (int ni = 0; ni < 4; ++ni)
                acc[j][ni] = __builtin_amdgcn_mfma_f32_16x16x32_bf16(
                    bres0[ni], afrX[j], acc[j][ni], 0, 0, 0);
        __builtin_amdgcn_s_setprio(0);
        SCHED0; BARRIER; SCHED0;

        // ---- p1: MFMA mi4-7 kh0; read afrX(A03kh1); stage B
#pragma unroll
        for (int j = 0; j < 4; ++j) afrX[j] = ds_read8(ab0 + aoff[j][1]);
        if (st) { stB(nb, 0, k1); stB(nb, 1, k1); stB(nb, 2, k1); stB(nb, 3, k1); }
        wlg<8>();
        SCHED0;
        __builtin_amdgcn_s_setprio(1);
#pragma unroll
        for (int j = 0; j < 4; ++j)
#pragma unroll
            for (int ni = 0; ni < 4; ++ni)
                acc[4 + j][ni] = __builtin_amdgcn_mfma_f32_16x16x32_bf16(
                    bres0[ni], afrY[j], acc[4 + j][ni], 0, 0, 0);
        __builtin_amdgcn_s_setprio(0);
        SCHED0; BARRIER; SCHED0;

        // ---- p2: MFMA mi0-3 kh1; read afrY(A47kh1); vmcnt(0) post-MFMA
#pragma unroll
        for (int j = 0; j < 4; ++j) afrY[j] = ds_read8(ab0 + aoff[4 + j][1]);
        wlg<4>();
        SCHED0;
        __builtin_amdgcn_s_setprio(1);
#pragma unroll
        for (int j = 0; j < 4; ++j)
#pragma unroll
            for (int ni = 0; ni < 4; ++ni)
                acc[j][ni] = __builtin_amdgcn_mfma_f32_16x16x32_bf16(
                    bres1[ni], afrX[j], acc[j][ni], 0, 0, 0);
        __builtin_amdgcn_s_setprio(0);
        SCHED0;
        if (st) wvm<0>();                // t+1 fully resident (issued p0/p1)
        BARRIER; SCHED0;

        // ---- p3: MFMA mi4-7 kh1; read afrX(A03kh0,t+1) + bres0(Bkh0,t+1)
        if (st) {
#pragma unroll
            for (int j = 0; j < 4; ++j) afrX[j] = ds_read8(abn + aoff[j][0]);
#pragma unroll
            for (int ni = 0; ni < 4; ++ni) bres0[ni] = ds_read8(bbn + boff[ni][0]);
            wlg<8>();
        } else wlg<0>();
        SCHED0;
        __builtin_amdgcn_s_setprio(1);
#pragma unroll
        for (int j = 0; j < 4; ++j)
#pragma unroll
            for (int ni = 0; ni < 4; ++ni)
                acc[4 + j][ni] = __builtin_amdgcn_mfma_f32_16x16x32_bf16(
                    bres1[ni], afrY[j], acc[4 + j][ni], 0, 0, 0);
        __builtin_amdgcn_s_setprio(0);
        SCHED0; BARRIER; SCHED0;
    }

    // epilogue: bf16 + bias + relu
    const int mbase = bm * 256 + wm * 128;
    const int nbase = bn * 256 + wn * 64;
#pragma unroll
    for (int mi = 0; mi < 8; ++mi) {
        const int m = mbase + mi * 16 + l16;
#pragma unroll
        for (int ni = 0; ni < 4; ++ni) {
            const int n0 = nbase + ni * 16 + quad * 4;
            const float4 bv = *(const float4*)&bias[n0];
            float v0 = fmaxf(acc[mi][ni][0] + bv.x, 0.f);
            float v1 = fmaxf(acc[mi][ni][1] + bv.y, 0.f);
            float v2 = fmaxf(acc[mi][ni][2] + bv.z, 0.f);
            float v3 = fmaxf(acc[mi][ni][3] + bv.w, 0.f);
            ushort4 o = { f2bf(v0), f2bf(v1), f2bf(v2), f2bf(v3) };
            *(ushort4*)&H[(size_t)m * N + n0] = o;
        }
    }
}

// ---------------------------------------------------------------------------
// GEMM2 (verbatim R11, passed): out = H @ W2t^T + b2, fp32. M=8192 N=1024
// K=4096. BM=256 BN=128 (grid 256 = 1/CU), 8 waves (4M x 2N), wave 64x64.
// Triple-buffered kh-split LDS; cross-tile frag read-ahead; staging 2 tiles
// ahead; uniform vmcnt(6)/lgkmcnt(8); one barrier per phase.
// ---------------------------------------------------------------------------
__global__ __launch_bounds__(512, 2)
void gemm2(const u16* __restrict__ A, const u16* __restrict__ Bt,
           const float* __restrict__ bias, float* __restrict__ Cout)
{
    constexpr int K = 4096, N = 1024;
    constexpr int ASZ = 2 * 256 * 32;    // u16 per buffer (32KB)
    constexpr int BSZ = 2 * 128 * 32;    // u16 per buffer (16KB)
    __shared__ __align__(16) u16 Alds[3 * ASZ];   // 96KB
    __shared__ __align__(16) u16 Blds[3 * BSZ];   // 48KB

    const int tid  = threadIdx.x;
    const int wave = tid >> 6;
    const int lane = tid & 63;
    const int quad = lane >> 4;
    const int l16  = lane & 15;
    const int key4 = (l16 >> 1) & 3;
    const int wm   = wave >> 1;          // 0..3
    const int wn   = wave & 1;           // 0..1

    const int id = blockIdx.x;
    const int bm = id & 31;
    const int bn = id >> 5;

    const u16* Ag = A  + (size_t)bm * 256 * K;
    const u16* Bg = Bt + (size_t)bn * 128 * K;

    auto stA = [&](int buf, int kh, int c, int k0) {
        const int row = c * 128 + wave * 16 + (lane >> 2);
        const int col = kh * 32 + ((lane & 3) ^ ((row >> 1) & 3)) * 8;
        __builtin_amdgcn_global_load_lds(
            (AS1 void*)(Ag + (size_t)row * K + k0 + col),
            (AS3 void*)(&Alds[buf * ASZ + kh * 8192 + c * 4096 + wave * 512]),
            16, 0, 0);
    };
    auto stB = [&](int buf, int kh, int k0) {
        const int row = wave * 16 + (lane >> 2);
        const int col = kh * 32 + ((lane & 3) ^ ((row >> 1) & 3)) * 8;
        __builtin_amdgcn_global_load_lds(
            (AS1 void*)(Bg + (size_t)row * K + k0 + col),
            (AS3 void*)(&Blds[buf * BSZ + kh * 4096 + wave * 512]), 16, 0, 0);
    };

    const unsigned Ab = lds_off(&Alds[0]);
    const unsigned Bb = lds_off(&Blds[0]);
    unsigned aoff[4], boff[4];
#pragma unroll
    for (int mi = 0; mi < 4; ++mi)
        aoff[mi] = ((wm * 64 + mi * 16 + l16) * 32 + (quad ^ key4) * 8) * 2;
#pragma unroll
    for (int ni = 0; ni < 4; ++ni)
        boff[ni] = ((wn * 64 + ni * 16 + l16) * 32 + (quad ^ key4) * 8) * 2;

    floatx4 acc[4][4];
#pragma unroll
    for (int i = 0; i < 4; ++i)
#pragma unroll
        for (int j = 0; j < 4; ++j)
            acc[i][j] = (floatx4){0.f, 0.f, 0.f, 0.f};

    constexpr int NT = K / 64;           // 64

    stA(0, 0, 0, 0);  stA(0, 0, 1, 0);  stB(0, 0, 0);
    stA(0, 1, 0, 0);  stA(0, 1, 1, 0);  stB(0, 1, 0);
    stA(1, 0, 0, 64); stA(1, 0, 1, 64); stB(1, 0, 64);
    stA(1, 1, 0, 64); stA(1, 1, 1, 64); stB(1, 1, 64);
    wvm<6>();
    SCHED0; BARRIER; SCHED0;

    bf16x8 fa[2][4], fb[2][4];
#pragma unroll
    for (int i = 0; i < 4; ++i) {
        fa[0][i] = ds_read8(Ab + aoff[i]);
        fb[0][i] = ds_read8(Bb + boff[i]);
    }

    int bs0 = 0, bs1 = 1, bs2 = 2;
    for (int t = 0; t < NT; ++t) {
        const int k2 = (t + 2) * 64;
        const bool st  = (t + 2 < NT);
        const bool rd1 = (t + 1 < NT);
        const unsigned a0 = Ab + (unsigned)(bs0 * ASZ * 2);
        const unsigned b0 = Bb + (unsigned)(bs0 * BSZ * 2);
        const unsigned a1 = Ab + (unsigned)(bs1 * ASZ * 2);
        const unsigned b1 = Bb + (unsigned)(bs1 * BSZ * 2);

        // phase kh=0
#pragma unroll
        for (int i = 0; i < 4; ++i) {
            fa[1][i] = ds_read8(a0 + 16384u + aoff[i]);
            fb[1][i] = ds_read8(b0 + 8192u  + boff[i]);
        }
        if (st) { stA(bs2, 0, 0, k2); stA(bs2, 0, 1, k2); stB(bs2, 0, k2); }
        wlg<8>();
        SCHED0;
        __builtin_amdgcn_s_setprio(1);
#pragma unroll
        for (int mi = 0; mi < 4; ++mi)
#pragma unroll
            for (int ni = 0; ni < 4; ++ni)
                acc[mi][ni] = __builtin_amdgcn_mfma_f32_16x16x32_bf16(
                    fb[0][ni], fa[0][mi], acc[mi][ni], 0, 0, 0);
        __builtin_amdgcn_s_setprio(0);
        SCHED0;
        if (st)       wvm<6>();
        else if (rd1) wvm<3>();
        BARRIER; SCHED0;

        // phase kh=1
        if (rd1) {
#pragma unroll
            for (int i = 0; i < 4; ++i) {
                fa[0][i] = ds_read8(a1 + aoff[i]);
                fb[0][i] = ds_read8(b1 + boff[i]);
            }
        }
        if (st) { stA(bs2, 1, 0, k2); stA(bs2, 1, 1, k2); stB(bs2, 1, k2); }
        if (rd1) wlg<8>(); else wlg<0>();
        SCHED0;
        __builtin_amdgcn_s_setprio(1);
#pragma unroll
        for (int mi = 0; mi < 4; ++mi)
#pragma unroll
            for (int ni = 0; ni < 4; ++ni)
                acc[mi][ni] = __builtin_amdgcn_mfma_f32_16x16x32_bf16(
                    fb[1][ni], fa[1][mi], acc[mi][ni], 0, 0, 0);
        __builtin_amdgcn_s_setprio(0);
        SCHED0;
        if (st)       wvm<6>();
        else if (rd1) wvm<0>();
        BARRIER; SCHED0;

        const int tmp = bs0; bs0 = bs1; bs1 = bs2; bs2 = tmp;
    }

    const int mbase = bm * 256 + wm * 64;
    const int nbase = bn * 128 + wn * 64;
#pragma unroll
    for (int mi = 0; mi < 4; ++mi) {
        const int m = mbase + mi * 16 + l16;
#pragma unroll
        for (int ni = 0; ni < 4; ++ni) {
            const int n0 = nbase + ni * 16 + quad * 4;
            const float4 bv = *(const float4*)&bias[n0];
            float4 o = { acc[mi][ni][0] + bv.x, acc[mi][ni][1] + bv.y,
                         acc[mi][ni][2] + bv.z, acc[mi][ni][3] + bv.w };
            *(float4*)&Cout[(size_t)m * N + n0] = o;
        }
    }
}

// ---------------------------------------------------------------------------
// inputs: 0 act(4,2048,1024) f32, 1 mask(unused), 2 ln_scale(1024),
//         3 ln_bias(1024), 4 w1(1024,4096), 5 b1(4096), 6 w2(4096,1024),
//         7 b2(1024). out: (4,2048,1024) f32.
// ws (bf16 bits): X[8192*1024] | W1t[4096*1024] | W2t[1024*4096] | H[8192*4096]
// ---------------------------------------------------------------------------
extern "C" void kernel_launch(void* const* d_in, const int* in_sizes, int n_in,
                              void* d_out, int out_size, void* d_ws, size_t ws_size,
                              hipStream_t stream)
{
    const float* act      = (const float*)d_in[0];
    const float* ln_scale = (const float*)d_in[2];
    const float* ln_bias  = (const float*)d_in[3];
    const float* w1       = (const float*)d_in[4];
    const float* b1       = (const float*)d_in[5];
    const float* w2       = (const float*)d_in[6];
    const float* b2       = (const float*)d_in[7];
    float* out = (float*)d_out;

    const int M = 8192, C = 1024, CI = 4096;

    u16* X   = (u16*)d_ws;                 // [M][C]
    u16* W1t = X   + (size_t)M * C;        // [CI][C]
    u16* W2t = W1t + (size_t)CI * C;       // [C][CI]
    u16* H   = W2t + (size_t)C * CI;       // [M][CI]

    prep<<<10240, 256, 0, stream>>>(w1, w2, act, ln_scale, ln_bias, W1t, W2t, X);
    // H = relu(X @ W1 + b1): 512 blocks, kh-major balanced 4-phase schedule
    gemm1<<<(M / 256) * (CI / 256), 512, 0, stream>>>(X, W1t, b1, H);
    // out = H @ W2 + b2: 256 blocks = 1/CU, cross-tile read-ahead (R11)
    gemm2<<<(M / 256) * (C / 128), 512, 0, stream>>>(H, W2t, b2, out);
}